// Round 1
// baseline (8849.102 us; speedup 1.0000x reference)
//
#include <hip/hip_runtime.h>

#define B_  64
#define T_  128
#define BT_ 8192
#define D_  2048
#define H_  1024
#define DD_ 512

typedef unsigned short u16t;
typedef __bf16 bf16x8 __attribute__((ext_vector_type(8)));
typedef float f32x4 __attribute__((ext_vector_type(4)));
typedef unsigned int u32x4 __attribute__((ext_vector_type(4)));

__device__ __forceinline__ u16t f2bf(float f) {
  unsigned u = __float_as_uint(f);
  u += 0x7fffu + ((u >> 16) & 1u);   // round-to-nearest-even
  return (u16t)(u >> 16);
}
__device__ __forceinline__ float bf2f(u16t h) {
  return __uint_as_float(((unsigned)h) << 16);
}
__device__ __forceinline__ float sigm(float x)  { return 1.0f / (1.0f + __expf(-x)); }
__device__ __forceinline__ float tanh_(float x) { return 1.0f - 2.0f / (1.0f + __expf(2.0f * x)); }

// ---------------- prep kernels ----------------
__global__ void k_prep_bt(const float* __restrict__ x, const float* __restrict__ fi,
                          u16t* __restrict__ bt16) {
  for (size_t i = (size_t)blockIdx.x * blockDim.x + threadIdx.x; i < (size_t)BT_ * D_;
       i += (size_t)gridDim.x * blockDim.x) {
    const size_t r = i >> 11;          // D_ = 2048
    const size_t d = i & (D_ - 1);
    bt16[i] = f2bf(x[i] * (1.0f - fi[(r * 2 + 1) * D_ + d]));
  }
}

__global__ void k_prep_dt(const float* __restrict__ fo, const int* __restrict__ mask,
                          u16t* __restrict__ dt16) {
  for (size_t i = (size_t)blockIdx.x * blockDim.x + threadIdx.x; i < (size_t)BT_ * DD_;
       i += (size_t)gridDim.x * blockDim.x) {
    const size_t r = i >> 9;           // DD_ = 512
    const int jj = (int)(i & (DD_ - 1));
    dt16[i] = f2bf(fo[(r * 2 + 1) * D_ + mask[jj]]);
  }
}

// in [K][N] fp32 -> out [N][K] bf16
__global__ void k_tr_cvt(const float* __restrict__ in, u16t* __restrict__ out, int K, int N) {
  const int total = K * N;
  for (int i = blockIdx.x * blockDim.x + threadIdx.x; i < total; i += gridDim.x * blockDim.x) {
    const int n = i / K;
    const int k = i - n * K;
    out[i] = f2bf(in[(size_t)k * N + n]);
  }
}

// in [K][N] fp32 -> out [N][K] fp32
__global__ void k_tr_f32(const float* __restrict__ in, float* __restrict__ out, int K, int N) {
  const int total = K * N;
  for (int i = blockIdx.x * blockDim.x + threadIdx.x; i < total; i += gridDim.x * blockDim.x) {
    const int n = i / K;
    const int k = i - n * K;
    out[i] = in[(size_t)k * N + n];
  }
}

// ---------------- MFMA GEMM ----------------
// C[M][N] = A[M][K] * B[K][N] with B given transposed: Bt[N][K], all bf16, fp32 acc.
// mode 0: outb[row*N+col] = bf16(acc + bias[col])
// mode 1: final epilogue: row=(t*64+b) -> out[(b*T+t)*D+col] = sigmoid(acc*(1+At)+eo)
__global__ __launch_bounds__(256) void k_gemm(
    const u16t* __restrict__ A, const u16t* __restrict__ Bt, int N, int K,
    const float* __restrict__ bias, u16t* __restrict__ outb, float* __restrict__ outf,
    const u16t* __restrict__ At16, const float* __restrict__ eo, int mode)
{
  __shared__ __align__(16) u16t As[64 * 32];
  __shared__ __align__(16) u16t Bs[64 * 32];
  const int m0 = blockIdx.x * 64;
  const int n0 = blockIdx.y * 64;
  const int t  = threadIdx.x;
  const int w  = t >> 6;
  const int l  = t & 63;
  const int wr = (w >> 1) * 32;     // wave quadrant row
  const int wc = (w & 1) * 32;      // wave quadrant col
  const int lr = l & 15;
  const int q  = l >> 4;
  const int srow = t >> 2;          // staging: 64 rows x 4 chunks of 8 bf16
  const int sc   = t & 3;
  const int spc  = (sc ^ (srow & 3)) * 8;   // XOR-swizzled physical chunk (store)
  const int rpc  = (q  ^ (lr  & 3)) * 8;    // XOR-swizzled physical chunk (read; row%4 == lr%4)

  f32x4 acc00 = {0.f, 0.f, 0.f, 0.f};
  f32x4 acc01 = acc00, acc10 = acc00, acc11 = acc00;
  const u16t* Ap = A  + (size_t)(m0 + srow) * K + sc * 8;
  const u16t* Bp = Bt + (size_t)(n0 + srow) * K + sc * 8;

  for (int k0 = 0; k0 < K; k0 += 32) {
    const u32x4 av = *(const u32x4*)(Ap + k0);
    const u32x4 bv = *(const u32x4*)(Bp + k0);
    __syncthreads();
    *(u32x4*)(As + srow * 32 + spc) = av;
    *(u32x4*)(Bs + srow * 32 + spc) = bv;
    __syncthreads();
    const bf16x8 a0 = *(const bf16x8*)(As + (wr + lr) * 32 + rpc);
    const bf16x8 a1 = *(const bf16x8*)(As + (wr + 16 + lr) * 32 + rpc);
    const bf16x8 b0 = *(const bf16x8*)(Bs + (wc + lr) * 32 + rpc);
    const bf16x8 b1 = *(const bf16x8*)(Bs + (wc + 16 + lr) * 32 + rpc);
    acc00 = __builtin_amdgcn_mfma_f32_16x16x32_bf16(a0, b0, acc00, 0, 0, 0);
    acc01 = __builtin_amdgcn_mfma_f32_16x16x32_bf16(a0, b1, acc01, 0, 0, 0);
    acc10 = __builtin_amdgcn_mfma_f32_16x16x32_bf16(a1, b0, acc10, 0, 0, 0);
    acc11 = __builtin_amdgcn_mfma_f32_16x16x32_bf16(a1, b1, acc11, 0, 0, 0);
  }

  f32x4 accs[2][2] = {{acc00, acc01}, {acc10, acc11}};
  #pragma unroll
  for (int im = 0; im < 2; ++im)
    #pragma unroll
    for (int in = 0; in < 2; ++in)
      #pragma unroll
      for (int r = 0; r < 4; ++r) {
        const int row = m0 + wr + im * 16 + q * 4 + r;   // C/D: row=(lane>>4)*4+reg
        const int col = n0 + wc + in * 16 + lr;          //       col=lane&15
        float v = accs[im][in][r];
        if (mode == 0) {
          if (bias) v += bias[col];
          outb[(size_t)row * N + col] = f2bf(v);
        } else {
          const int tt = row >> 6;        // row = t*64 + b
          const int bb = row & 63;
          const size_t o = ((size_t)bb * T_ + tt) * (size_t)D_ + col;
          outf[o] = sigm(v * (1.0f + bf2f(At16[o])) + eo[col]);
        }
      }
}

// ---------------- recurrence ----------------
__device__ __forceinline__ void gbar(unsigned* cnt, unsigned* gen) {
  __syncthreads();
  if (threadIdx.x == 0) {
    __threadfence();
    unsigned g0 = __hip_atomic_load(gen, __ATOMIC_RELAXED, __HIP_MEMORY_SCOPE_AGENT);
    unsigned a = __hip_atomic_fetch_add(cnt, 1u, __ATOMIC_ACQ_REL, __HIP_MEMORY_SCOPE_AGENT);
    if (a == 63u) {
      __hip_atomic_store(cnt, 0u, __ATOMIC_RELAXED, __HIP_MEMORY_SCOPE_AGENT);
      __hip_atomic_fetch_add(gen, 1u, __ATOMIC_RELEASE, __HIP_MEMORY_SCOPE_AGENT);
    } else {
      while (__hip_atomic_load(gen, __ATOMIC_RELAXED, __HIP_MEMORY_SCOPE_AGENT) == g0) {
        __builtin_amdgcn_s_sleep(2);
      }
    }
    __threadfence();
  }
  __syncthreads();
}

// grid: 256 blocks x 256 threads, block = (batch-group g of 16, col-tile c of 16)
// LDS hs[16][1024] holds the group's h (then h*s) with rotation skew to avoid
// 16-way bank conflicts on the strided dot-product reads.
#define SKEW(bb, kk) ((bb) * 1024 + (((kk) + (bb) * 4) & 1023))

__global__ __launch_bounds__(256) void k_recur(
    const u16t* __restrict__ pf16, const u16t* __restrict__ ps16, const u16t* __restrict__ pi16,
    const float* __restrict__ Wfat, const float* __restrict__ Wsat, const float* __restrict__ Wiat,
    u16t* __restrict__ h16, u16t* __restrict__ s16, u16t* __restrict__ hist16,
    unsigned* bar)
{
  __shared__ __align__(16) float hs[16 * 1024];   // 64 KB
  const int g  = blockIdx.x >> 6;
  const int c  = blockIdx.x & 63;
  const int t  = threadIdx.x;
  const int tb = t & 15;          // batch within group
  const int tj = t >> 4;          // col within tile (wave-uniform groups of 4 j's)
  const int b  = g * 16 + tb;
  const int j  = c * 16 + tj;
  unsigned* cnt = bar + g * 64;
  unsigned* gen = bar + g * 64 + 32;

  const float* wfp = Wfat + (size_t)j * H_;
  const float* wsp = Wsat + (size_t)j * H_;
  const float* wip = Wiat + (size_t)j * H_;

  float h_reg = 0.0f;
  for (int i = t; i < 16 * H_; i += 256) hs[i] = 0.0f;
  __syncthreads();

  for (int step = 0; step < T_; ++step) {
    // ---- part A: f and s gates (needs full h of this batch group) ----
    float df = 0.0f, dsv = 0.0f;
    #pragma unroll 4
    for (int k = 0; k < H_; k += 4) {
      const float4 hv  = *(const float4*)&hs[SKEW(tb, k)];
      const float4 wfv = *(const float4*)&wfp[k];
      const float4 wsv = *(const float4*)&wsp[k];
      df  += hv.x * wfv.x + hv.y * wfv.y + hv.z * wfv.z + hv.w * wfv.w;
      dsv += hv.x * wsv.x + hv.y * wsv.y + hv.z * wsv.z + hv.w * wsv.w;
    }
    const size_t prow = ((size_t)b * T_ + step) * H_ + j;
    const float fg = sigm(bf2f(pf16[prow]) + df);
    const float sg = sigm(bf2f(ps16[prow]) + dsv);
    s16[b * H_ + j] = f2bf(sg);
    gbar(cnt, gen);

    // ---- part B: hs := h .* s, then c gate + h update ----
    for (int ii = t; ii < 16 * 128; ii += 256) {
      const int bb = ii >> 7;
      const int kc = (ii & 127) * 8;
      u32x4 sv = *(const u32x4*)&s16[(g * 16 + bb) * H_ + kc];
      const u16t* pu = (const u16t*)&sv;
      float* p0 = &hs[SKEW(bb, kc)];
      float* p1 = &hs[SKEW(bb, kc + 4)];
      p0[0] *= bf2f(pu[0]); p0[1] *= bf2f(pu[1]); p0[2] *= bf2f(pu[2]); p0[3] *= bf2f(pu[3]);
      p1[0] *= bf2f(pu[4]); p1[1] *= bf2f(pu[5]); p1[2] *= bf2f(pu[6]); p1[3] *= bf2f(pu[7]);
    }
    __syncthreads();

    float dc = 0.0f;
    #pragma unroll 4
    for (int k = 0; k < H_; k += 4) {
      const float4 hv  = *(const float4*)&hs[SKEW(tb, k)];
      const float4 wiv = *(const float4*)&wip[k];
      dc += hv.x * wiv.x + hv.y * wiv.y + hv.z * wiv.z + hv.w * wiv.w;
    }
    const float cg = tanh_(bf2f(pi16[prow]) + dc);
    h_reg = h_reg * (1.0f - fg) + fg * cg;     // exact fp32 carried state
    const u16t hb = f2bf(h_reg);
    h16[b * H_ + j] = hb;
    hist16[((size_t)step * B_ + b) * H_ + j] = hb;
    gbar(cnt, gen);

    // ---- restage h (next step's operand) into LDS ----
    for (int ii = t; ii < 16 * 128; ii += 256) {
      const int bb = ii >> 7;
      const int kc = (ii & 127) * 8;
      u32x4 hv = *(const u32x4*)&h16[(g * 16 + bb) * H_ + kc];
      const u16t* pu = (const u16t*)&hv;
      float* p0 = &hs[SKEW(bb, kc)];
      float* p1 = &hs[SKEW(bb, kc + 4)];
      p0[0] = bf2f(pu[0]); p0[1] = bf2f(pu[1]); p0[2] = bf2f(pu[2]); p0[3] = bf2f(pu[3]);
      p1[0] = bf2f(pu[4]); p1[1] = bf2f(pu[5]); p1[2] = bf2f(pu[6]); p1[3] = bf2f(pu[7]);
    }
    __syncthreads();
  }
}

// ---------------- host ----------------
extern "C" void kernel_launch(void* const* d_in, const int* in_sizes, int n_in,
                              void* d_out, int out_size, void* d_ws, size_t ws_size,
                              hipStream_t stream)
{
  const float* x    = (const float*)d_in[0];
  const float* fo   = (const float*)d_in[1];
  const float* fi   = (const float*)d_in[2];
  const float* Wfb  = (const float*)d_in[3];
  const float* Wfa  = (const float*)d_in[4];
  const float* ef   = (const float*)d_in[5];
  const float* Wib  = (const float*)d_in[6];
  const float* Wia  = (const float*)d_in[7];
  const float* ei   = (const float*)d_in[8];
  const float* Wsb  = (const float*)d_in[9];
  const float* Wsa  = (const float*)d_in[10];
  const float* es   = (const float*)d_in[11];
  const float* Wba  = (const float*)d_in[12];
  const float* eo   = (const float*)d_in[13];
  const float* E    = (const float*)d_in[14];
  const int*   mask = (const int*)d_in[15];
  float* out = (float*)d_out;

  char* p = (char*)d_ws;
  auto alloc = [&](size_t bytes) { char* r = p; p += (bytes + 255) & ~(size_t)255; return r; };
  unsigned* bar = (unsigned*)alloc(4096);
  u16t* bt16   = (u16t*)alloc((size_t)BT_ * D_ * 2);
  u16t* dt16   = (u16t*)alloc((size_t)BT_ * DD_ * 2);
  u16t* Wfbt   = (u16t*)alloc((size_t)H_ * D_ * 2);
  u16t* Wsbt   = (u16t*)alloc((size_t)H_ * D_ * 2);
  u16t* Wibt   = (u16t*)alloc((size_t)H_ * D_ * 2);
  u16t* Et     = (u16t*)alloc((size_t)D_ * DD_ * 2);
  u16t* Wbat   = (u16t*)alloc((size_t)D_ * H_ * 2);
  u16t* pf16   = (u16t*)alloc((size_t)BT_ * H_ * 2);
  u16t* ps16   = (u16t*)alloc((size_t)BT_ * H_ * 2);
  u16t* pi16   = (u16t*)alloc((size_t)BT_ * H_ * 2);
  u16t* At16   = (u16t*)alloc((size_t)BT_ * D_ * 2);
  float* Wfat  = (float*)alloc((size_t)H_ * H_ * 4);
  float* Wsat  = (float*)alloc((size_t)H_ * H_ * 4);
  float* Wiat  = (float*)alloc((size_t)H_ * H_ * 4);
  u16t* h16    = (u16t*)alloc((size_t)B_ * H_ * 2);
  u16t* s16    = (u16t*)alloc((size_t)B_ * H_ * 2);
  u16t* hist16 = (u16t*)alloc((size_t)BT_ * H_ * 2);

  hipMemsetAsync(bar, 0, 4096, stream);

  k_prep_bt<<<4096, 256, 0, stream>>>(x, fi, bt16);
  k_prep_dt<<<2048, 256, 0, stream>>>(fo, mask, dt16);
  k_tr_cvt<<<2048, 256, 0, stream>>>(Wfb, Wfbt, D_, H_);
  k_tr_cvt<<<2048, 256, 0, stream>>>(Wsb, Wsbt, D_, H_);
  k_tr_cvt<<<2048, 256, 0, stream>>>(Wib, Wibt, D_, H_);
  k_tr_cvt<<<1024, 256, 0, stream>>>(E, Et, DD_, D_);
  k_tr_cvt<<<2048, 256, 0, stream>>>(Wba, Wbat, H_, D_);
  k_tr_f32<<<1024, 256, 0, stream>>>(Wfa, Wfat, H_, H_);
  k_tr_f32<<<1024, 256, 0, stream>>>(Wsa, Wsat, H_, H_);
  k_tr_f32<<<1024, 256, 0, stream>>>(Wia, Wiat, H_, H_);

  // pf = bt@Wfb + ef ; ps = bt@Wsb + es ; pi = bt@Wib + ei
  k_gemm<<<dim3(BT_ / 64, H_ / 64), 256, 0, stream>>>(bt16, Wfbt, H_, D_, ef, pf16, nullptr, nullptr, nullptr, 0);
  k_gemm<<<dim3(BT_ / 64, H_ / 64), 256, 0, stream>>>(bt16, Wsbt, H_, D_, es, ps16, nullptr, nullptr, nullptr, 0);
  k_gemm<<<dim3(BT_ / 64, H_ / 64), 256, 0, stream>>>(bt16, Wibt, H_, D_, ei, pi16, nullptr, nullptr, nullptr, 0);
  // At = dt@E
  k_gemm<<<dim3(BT_ / 64, D_ / 64), 256, 0, stream>>>(dt16, Et, D_, DD_, nullptr, At16, nullptr, nullptr, nullptr, 0);

  // sequential recurrence (cooperative; per-batch-group barriers)
  void* args[10];
  args[0] = &pf16; args[1] = &ps16; args[2] = &pi16;
  args[3] = &Wfat; args[4] = &Wsat; args[5] = &Wiat;
  args[6] = &h16;  args[7] = &s16;  args[8] = &hist16;
  args[9] = &bar;
  hipLaunchCooperativeKernel((void*)k_recur, dim3(256), dim3(256), args, 0, stream);

  // out = sigmoid((h_hist@W_ba) * (1+At) + e_o)
  k_gemm<<<dim3(BT_ / 64, D_ / 64), 256, 0, stream>>>(hist16, Wbat, D_, H_, nullptr, nullptr, out, At16, eo, 1);
}

// Round 2
// 5810.814 us; speedup vs baseline: 1.5229x; 1.5229x over previous
//
#include <hip/hip_runtime.h>

#define B_  64
#define T_  128
#define BT_ 8192
#define D_  2048
#define H_  1024
#define DD_ 512

typedef unsigned short u16t;
typedef __bf16 bf16x8 __attribute__((ext_vector_type(8)));
typedef float f32x4 __attribute__((ext_vector_type(4)));
typedef unsigned int u32x4 __attribute__((ext_vector_type(4)));

__device__ __forceinline__ u16t f2bf(float f) {
  unsigned u = __float_as_uint(f);
  u += 0x7fffu + ((u >> 16) & 1u);   // round-to-nearest-even
  return (u16t)(u >> 16);
}
__device__ __forceinline__ float bf2f(u16t h) {
  return __uint_as_float(((unsigned)h) << 16);
}
__device__ __forceinline__ float sigm(float x)  { return 1.0f / (1.0f + __expf(-x)); }
__device__ __forceinline__ float tanh_(float x) { return 1.0f - 2.0f / (1.0f + __expf(2.0f * x)); }

// ---------------- prep kernels ----------------
__global__ void k_prep_bt(const float* __restrict__ x, const float* __restrict__ fi,
                          u16t* __restrict__ bt16) {
  for (size_t i = (size_t)blockIdx.x * blockDim.x + threadIdx.x; i < (size_t)BT_ * D_;
       i += (size_t)gridDim.x * blockDim.x) {
    const size_t r = i >> 11;          // D_ = 2048
    const size_t d = i & (D_ - 1);
    bt16[i] = f2bf(x[i] * (1.0f - fi[(r * 2 + 1) * D_ + d]));
  }
}

__global__ void k_prep_dt(const float* __restrict__ fo, const int* __restrict__ mask,
                          u16t* __restrict__ dt16) {
  for (size_t i = (size_t)blockIdx.x * blockDim.x + threadIdx.x; i < (size_t)BT_ * DD_;
       i += (size_t)gridDim.x * blockDim.x) {
    const size_t r = i >> 9;           // DD_ = 512
    const int jj = (int)(i & (DD_ - 1));
    dt16[i] = f2bf(fo[(r * 2 + 1) * D_ + mask[jj]]);
  }
}

// in [K][N] fp32 -> out [N][K] bf16
__global__ void k_tr_cvt(const float* __restrict__ in, u16t* __restrict__ out, int K, int N) {
  const int total = K * N;
  for (int i = blockIdx.x * blockDim.x + threadIdx.x; i < total; i += gridDim.x * blockDim.x) {
    const int n = i / K;
    const int k = i - n * K;
    out[i] = f2bf(in[(size_t)k * N + n]);
  }
}

// ---------------- MFMA GEMM ----------------
// C[M][N] = A[M][K] * B[K][N] with B given transposed: Bt[N][K], all bf16, fp32 acc.
// mode 0: outb[row*N+col] = bf16(acc + bias[col])
// mode 1: final epilogue: row=(t*64+b) -> out[(b*T+t)*D+col] = sigmoid(acc*(1+At)+eo)
__global__ __launch_bounds__(256) void k_gemm(
    const u16t* __restrict__ A, const u16t* __restrict__ Bt, int N, int K,
    const float* __restrict__ bias, u16t* __restrict__ outb, float* __restrict__ outf,
    const u16t* __restrict__ At16, const float* __restrict__ eo, int mode)
{
  __shared__ __align__(16) u16t As[64 * 32];
  __shared__ __align__(16) u16t Bs[64 * 32];
  const int m0 = blockIdx.x * 64;
  const int n0 = blockIdx.y * 64;
  const int t  = threadIdx.x;
  const int w  = t >> 6;
  const int l  = t & 63;
  const int wr = (w >> 1) * 32;     // wave quadrant row
  const int wc = (w & 1) * 32;      // wave quadrant col
  const int lr = l & 15;
  const int q  = l >> 4;
  const int srow = t >> 2;          // staging: 64 rows x 4 chunks of 8 bf16
  const int sc   = t & 3;
  const int spc  = (sc ^ (srow & 3)) * 8;   // XOR-swizzled physical chunk (store)
  const int rpc  = (q  ^ (lr  & 3)) * 8;    // XOR-swizzled physical chunk (read)

  f32x4 acc00 = {0.f, 0.f, 0.f, 0.f};
  f32x4 acc01 = acc00, acc10 = acc00, acc11 = acc00;
  const u16t* Ap = A  + (size_t)(m0 + srow) * K + sc * 8;
  const u16t* Bp = Bt + (size_t)(n0 + srow) * K + sc * 8;

  for (int k0 = 0; k0 < K; k0 += 32) {
    const u32x4 av = *(const u32x4*)(Ap + k0);
    const u32x4 bv = *(const u32x4*)(Bp + k0);
    __syncthreads();
    *(u32x4*)(As + srow * 32 + spc) = av;
    *(u32x4*)(Bs + srow * 32 + spc) = bv;
    __syncthreads();
    const bf16x8 a0 = *(const bf16x8*)(As + (wr + lr) * 32 + rpc);
    const bf16x8 a1 = *(const bf16x8*)(As + (wr + 16 + lr) * 32 + rpc);
    const bf16x8 b0 = *(const bf16x8*)(Bs + (wc + lr) * 32 + rpc);
    const bf16x8 b1 = *(const bf16x8*)(Bs + (wc + 16 + lr) * 32 + rpc);
    acc00 = __builtin_amdgcn_mfma_f32_16x16x32_bf16(a0, b0, acc00, 0, 0, 0);
    acc01 = __builtin_amdgcn_mfma_f32_16x16x32_bf16(a0, b1, acc01, 0, 0, 0);
    acc10 = __builtin_amdgcn_mfma_f32_16x16x32_bf16(a1, b0, acc10, 0, 0, 0);
    acc11 = __builtin_amdgcn_mfma_f32_16x16x32_bf16(a1, b1, acc11, 0, 0, 0);
  }

  f32x4 accs[2][2] = {{acc00, acc01}, {acc10, acc11}};
  #pragma unroll
  for (int im = 0; im < 2; ++im)
    #pragma unroll
    for (int in = 0; in < 2; ++in)
      #pragma unroll
      for (int r = 0; r < 4; ++r) {
        const int row = m0 + wr + im * 16 + q * 4 + r;   // C/D: row=(lane>>4)*4+reg
        const int col = n0 + wc + in * 16 + lr;          //       col=lane&15
        float v = accs[im][in][r];
        if (mode == 0) {
          if (bias) v += bias[col];
          outb[(size_t)row * N + col] = f2bf(v);
        } else {
          const int tt = row >> 6;        // row = t*64 + b
          const int bb = row & 63;
          const size_t o = ((size_t)bb * T_ + tt) * (size_t)D_ + col;
          outf[o] = sigm(v * (1.0f + bf2f(At16[o])) + eo[col]);
        }
      }
}

// ---------------- recurrence ----------------
// Per-row-group barrier (64 blocks). Device-scope: release own stores to L3,
// invalidate L1/L2 on the way out so post-barrier reads see other XCDs' writes.
__device__ __forceinline__ void gbar(unsigned* cnt, unsigned* gen) {
  __syncthreads();
  if (threadIdx.x == 0) {
    __threadfence();
    unsigned g0 = __hip_atomic_load(gen, __ATOMIC_RELAXED, __HIP_MEMORY_SCOPE_AGENT);
    unsigned a = __hip_atomic_fetch_add(cnt, 1u, __ATOMIC_ACQ_REL, __HIP_MEMORY_SCOPE_AGENT);
    if (a == 63u) {
      __hip_atomic_store(cnt, 0u, __ATOMIC_RELAXED, __HIP_MEMORY_SCOPE_AGENT);
      __hip_atomic_fetch_add(gen, 1u, __ATOMIC_RELEASE, __HIP_MEMORY_SCOPE_AGENT);
    } else {
      while (__hip_atomic_load(gen, __ATOMIC_RELAXED, __HIP_MEMORY_SCOPE_AGENT) == g0) {
        __builtin_amdgcn_s_sleep(1);
      }
    }
    __threadfence();
  }
  __syncthreads();
}

// Grid: 256 blocks x 256 threads. block = (row-group g of 16 batch rows) x (col-tile jb of 16).
// Wave w owns K-slice [w*256,(w+1)*256); weight B-frags persistent in VGPRs (96 regs).
// Wave 0 holds exact fp32 h state in MFMA C-layout regs for (rows m0+q*4+r, col j0+lr).
// Barriers couple only the 64 blocks sharing a row-group (rows are independent).
__global__ __launch_bounds__(256) void k_recur(
    const u16t* __restrict__ pf16, const u16t* __restrict__ ps16, const u16t* __restrict__ pi16,
    const u16t* __restrict__ Wft, const u16t* __restrict__ Wst, const u16t* __restrict__ Wit,
    u16t* __restrict__ h16, u16t* __restrict__ hs16, u16t* __restrict__ hist16,
    unsigned* bar)
{
  __shared__ __align__(16) float red[2 * 4 * 64 * 4];   // [gate][wave][lane][4] = 8 KB
  const int g  = blockIdx.x >> 6;
  const int jb = blockIdx.x & 63;
  const int t  = threadIdx.x;
  const int w  = t >> 6;
  const int l  = t & 63;
  const int lr = l & 15;
  const int q  = l >> 4;
  const int m0 = g * 16;
  const int j0 = jb * 16;
  unsigned* cnt = bar + g * 64;
  unsigned* gen = cnt + 32;

  // persistent weight fragments: 3 gates x 8 k-chunks x 4 VGPR
  bf16x8 Bf[8], Bs[8], Bi[8];
  {
    const size_t wb = (size_t)(j0 + lr) * H_ + w * 256 + q * 8;
    #pragma unroll
    for (int kc = 0; kc < 8; ++kc) {
      Bf[kc] = *(const bf16x8*)(Wft + wb + (size_t)kc * 32);
      Bs[kc] = *(const bf16x8*)(Wst + wb + (size_t)kc * 32);
      Bi[kc] = *(const bf16x8*)(Wit + wb + (size_t)kc * 32);
    }
  }

  float h_reg[4] = {0.f, 0.f, 0.f, 0.f};
  float f_reg[4] = {0.f, 0.f, 0.f, 0.f};

  // zero this group's rows of h16 (group-local write => group barrier suffices)
  h16[(size_t)m0 * H_ + jb * 256 + t] = 0;
  gbar(cnt, gen);

  const size_t arow = (size_t)(m0 + lr) * H_ + w * 256 + q * 8;

  for (int step = 0; step < T_; ++step) {
    // ---- phase A: f, s gates ----
    // hoist the small pf/ps loads so they overlap the MFMA frag loads
    float pfv[4], psv[4];
    #pragma unroll
    for (int r = 0; r < 4; ++r) {
      const size_t prow = ((size_t)(m0 + q * 4 + r) * T_ + step) * H_ + j0 + lr;
      pfv[r] = bf2f(pf16[prow]);
      psv[r] = bf2f(ps16[prow]);
    }
    f32x4 accf = {0.f, 0.f, 0.f, 0.f}, accs = accf;
    #pragma unroll
    for (int kc = 0; kc < 8; ++kc) {
      const bf16x8 a = *(const bf16x8*)(h16 + arow + (size_t)kc * 32);
      accf = __builtin_amdgcn_mfma_f32_16x16x32_bf16(a, Bf[kc], accf, 0, 0, 0);
      accs = __builtin_amdgcn_mfma_f32_16x16x32_bf16(a, Bs[kc], accs, 0, 0, 0);
    }
    *(f32x4*)&red[(0 * 4 + w) * 256 + l * 4] = accf;
    *(f32x4*)&red[(1 * 4 + w) * 256 + l * 4] = accs;
    __syncthreads();
    if (w == 0) {
      f32x4 sf = *(const f32x4*)&red[(0 * 4 + 0) * 256 + l * 4];
      f32x4 ss = *(const f32x4*)&red[(1 * 4 + 0) * 256 + l * 4];
      #pragma unroll
      for (int ww = 1; ww < 4; ++ww) {
        sf += *(const f32x4*)&red[(0 * 4 + ww) * 256 + l * 4];
        ss += *(const f32x4*)&red[(1 * 4 + ww) * 256 + l * 4];
      }
      #pragma unroll
      for (int r = 0; r < 4; ++r) {
        const int m = m0 + q * 4 + r;
        const float fv = sigm(pfv[r] + sf[r]);
        const float sv = sigm(psv[r] + ss[r]);
        f_reg[r] = fv;
        hs16[(size_t)m * H_ + j0 + lr] = f2bf(h_reg[r] * sv);   // hs = h .* s (h exact fp32)
      }
    }
    gbar(cnt, gen);   // publish hs

    // ---- phase B: c gate + h update ----
    float piv[4];
    #pragma unroll
    for (int r = 0; r < 4; ++r) {
      const size_t prow = ((size_t)(m0 + q * 4 + r) * T_ + step) * H_ + j0 + lr;
      piv[r] = bf2f(pi16[prow]);
    }
    f32x4 acci = {0.f, 0.f, 0.f, 0.f};
    #pragma unroll
    for (int kc = 0; kc < 8; ++kc) {
      const bf16x8 a = *(const bf16x8*)(hs16 + arow + (size_t)kc * 32);
      acci = __builtin_amdgcn_mfma_f32_16x16x32_bf16(a, Bi[kc], acci, 0, 0, 0);
    }
    *(f32x4*)&red[w * 256 + l * 4] = acci;
    __syncthreads();
    if (w == 0) {
      f32x4 sc = *(const f32x4*)&red[l * 4];
      #pragma unroll
      for (int ww = 1; ww < 4; ++ww) sc += *(const f32x4*)&red[ww * 256 + l * 4];
      #pragma unroll
      for (int r = 0; r < 4; ++r) {
        const int m = m0 + q * 4 + r;
        const float cv = tanh_(piv[r] + sc[r]);
        h_reg[r] = h_reg[r] * (1.f - f_reg[r]) + f_reg[r] * cv;
        const u16t hb = f2bf(h_reg[r]);
        h16[(size_t)m * H_ + j0 + lr] = hb;
        hist16[((size_t)step * B_ + m) * H_ + j0 + lr] = hb;
      }
    }
    gbar(cnt, gen);   // publish h
  }
}

// ---------------- host ----------------
extern "C" void kernel_launch(void* const* d_in, const int* in_sizes, int n_in,
                              void* d_out, int out_size, void* d_ws, size_t ws_size,
                              hipStream_t stream)
{
  const float* x    = (const float*)d_in[0];
  const float* fo   = (const float*)d_in[1];
  const float* fi   = (const float*)d_in[2];
  const float* Wfb  = (const float*)d_in[3];
  const float* Wfa  = (const float*)d_in[4];
  const float* ef   = (const float*)d_in[5];
  const float* Wib  = (const float*)d_in[6];
  const float* Wia  = (const float*)d_in[7];
  const float* ei   = (const float*)d_in[8];
  const float* Wsb  = (const float*)d_in[9];
  const float* Wsa  = (const float*)d_in[10];
  const float* es   = (const float*)d_in[11];
  const float* Wba  = (const float*)d_in[12];
  const float* eo   = (const float*)d_in[13];
  const float* E    = (const float*)d_in[14];
  const int*   mask = (const int*)d_in[15];
  float* out = (float*)d_out;

  char* p = (char*)d_ws;
  auto alloc = [&](size_t bytes) { char* r = p; p += (bytes + 255) & ~(size_t)255; return r; };
  unsigned* bar = (unsigned*)alloc(4096);
  u16t* bt16   = (u16t*)alloc((size_t)BT_ * D_ * 2);
  u16t* dt16   = (u16t*)alloc((size_t)BT_ * DD_ * 2);
  u16t* Wfbt   = (u16t*)alloc((size_t)H_ * D_ * 2);
  u16t* Wsbt   = (u16t*)alloc((size_t)H_ * D_ * 2);
  u16t* Wibt   = (u16t*)alloc((size_t)H_ * D_ * 2);
  u16t* Et     = (u16t*)alloc((size_t)D_ * DD_ * 2);
  u16t* Wbat   = (u16t*)alloc((size_t)D_ * H_ * 2);
  u16t* pf16   = (u16t*)alloc((size_t)BT_ * H_ * 2);
  u16t* ps16   = (u16t*)alloc((size_t)BT_ * H_ * 2);
  u16t* pi16   = (u16t*)alloc((size_t)BT_ * H_ * 2);
  u16t* At16   = (u16t*)alloc((size_t)BT_ * D_ * 2);
  u16t* Wft    = (u16t*)alloc((size_t)H_ * H_ * 2);
  u16t* Wst    = (u16t*)alloc((size_t)H_ * H_ * 2);
  u16t* Wit    = (u16t*)alloc((size_t)H_ * H_ * 2);
  u16t* h16    = (u16t*)alloc((size_t)B_ * H_ * 2);
  u16t* hs16   = (u16t*)alloc((size_t)B_ * H_ * 2);
  u16t* hist16 = (u16t*)alloc((size_t)BT_ * H_ * 2);

  hipMemsetAsync(bar, 0, 4096, stream);

  k_prep_bt<<<4096, 256, 0, stream>>>(x, fi, bt16);
  k_prep_dt<<<2048, 256, 0, stream>>>(fo, mask, dt16);
  k_tr_cvt<<<2048, 256, 0, stream>>>(Wfb, Wfbt, D_, H_);
  k_tr_cvt<<<2048, 256, 0, stream>>>(Wsb, Wsbt, D_, H_);
  k_tr_cvt<<<2048, 256, 0, stream>>>(Wib, Wibt, D_, H_);
  k_tr_cvt<<<1024, 256, 0, stream>>>(E, Et, DD_, D_);
  k_tr_cvt<<<2048, 256, 0, stream>>>(Wba, Wbat, H_, D_);
  k_tr_cvt<<<1024, 256, 0, stream>>>(Wfa, Wft, H_, H_);
  k_tr_cvt<<<1024, 256, 0, stream>>>(Wsa, Wst, H_, H_);
  k_tr_cvt<<<1024, 256, 0, stream>>>(Wia, Wit, H_, H_);

  // pf = bt@Wfb + ef ; ps = bt@Wsb + es ; pi = bt@Wib + ei
  k_gemm<<<dim3(BT_ / 64, H_ / 64), 256, 0, stream>>>(bt16, Wfbt, H_, D_, ef, pf16, nullptr, nullptr, nullptr, 0);
  k_gemm<<<dim3(BT_ / 64, H_ / 64), 256, 0, stream>>>(bt16, Wsbt, H_, D_, es, ps16, nullptr, nullptr, nullptr, 0);
  k_gemm<<<dim3(BT_ / 64, H_ / 64), 256, 0, stream>>>(bt16, Wibt, H_, D_, ei, pi16, nullptr, nullptr, nullptr, 0);
  // At = dt@E
  k_gemm<<<dim3(BT_ / 64, D_ / 64), 256, 0, stream>>>(dt16, Et, D_, DD_, nullptr, At16, nullptr, nullptr, nullptr, 0);

  // sequential recurrence (cooperative; per-row-group barriers, MFMA gates,
  // weights persistent in registers)
  void* args[10];
  args[0] = &pf16; args[1] = &ps16; args[2] = &pi16;
  args[3] = &Wft;  args[4] = &Wst;  args[5] = &Wit;
  args[6] = &h16;  args[7] = &hs16; args[8] = &hist16;
  args[9] = &bar;
  hipLaunchCooperativeKernel((void*)k_recur, dim3(256), dim3(256), args, 0, stream);

  // out = sigmoid((h_hist@W_ba) * (1+At) + e_o)
  k_gemm<<<dim3(BT_ / 64, D_ / 64), 256, 0, stream>>>(hist16, Wbat, D_, H_, nullptr, nullptr, out, At16, eo, 1);
}